// Round 7
// baseline (530.987 us; speedup 1.0000x reference)
//
#include <hip/hip_runtime.h>
#include <hip/hip_bf16.h>

#define HD 1024      // H
#define K2 2048      // 2H
#define BATCH 32
#define SEQ 2048
#define M_TOT (BATCH * SEQ)  // 65536

typedef __attribute__((ext_vector_type(4))) float f32x4;
typedef __attribute__((ext_vector_type(8))) short bf16x8;
typedef __attribute__((ext_vector_type(4))) unsigned short u16x4;
typedef __attribute__((ext_vector_type(8))) unsigned short u16x8;

__device__ __forceinline__ float bf2f(unsigned short u) {
    unsigned int x = ((unsigned int)u) << 16;
    return __builtin_bit_cast(float, x);
}
__device__ __forceinline__ unsigned short f2bf(float f) {
    unsigned int x = __builtin_bit_cast(unsigned int, f);
    unsigned int lsb = (x >> 16) & 1u;
    x += 0x7fffu + lsb;   // round to nearest even
    return (unsigned short)(x >> 16);
}

__device__ __forceinline__ void load_lds_16B(const void* g, void* lds) {
    __builtin_amdgcn_global_load_lds(
        (const __attribute__((address_space(1))) unsigned int*)g,
        (__attribute__((address_space(3))) unsigned int*)lds,
        16, 0, 0);
}

// ---------------- value f32 -> bf16 streaming convert ----------------
__global__ __launch_bounds__(256) void cvt_value_kernel(
        const float* __restrict__ A, unsigned short* __restrict__ Abf) {
    const size_t stride = (size_t)2048 * 256 * 8;
    size_t i = ((size_t)blockIdx.x * 256 + threadIdx.x) * 8;
    const size_t n = (size_t)M_TOT * K2;
    for (; i < n; i += stride) {
        f32x4 a = *reinterpret_cast<const f32x4*>(A + i);
        f32x4 b = *reinterpret_cast<const f32x4*>(A + i + 4);
        u16x8 r;
        r[0] = f2bf(a.x); r[1] = f2bf(a.y); r[2] = f2bf(a.z); r[3] = f2bf(a.w);
        r[4] = f2bf(b.x); r[5] = f2bf(b.y); r[6] = f2bf(b.z); r[7] = f2bf(b.w);
        *reinterpret_cast<u16x8*>(Abf + i) = r;
    }
}

// ---------------- Wv [K2,HD] f32  ->  WvT [HD,K2] bf16 ----------------
__global__ __launch_bounds__(256) void wv_transpose_kernel(
        const float* __restrict__ Wv, unsigned short* __restrict__ WvT) {
    __shared__ float t[64][65];
    int n0 = blockIdx.x * 64;
    int k0 = blockIdx.y * 64;
    int tx = threadIdx.x & 63, ty = threadIdx.x >> 6;
#pragma unroll
    for (int rr = 0; rr < 16; ++rr) {
        int row = ty + rr * 4;
        t[row][tx] = Wv[(size_t)(k0 + row) * HD + n0 + tx];
    }
    __syncthreads();
#pragma unroll
    for (int rr = 0; rr < 16; ++rr) {
        int row = ty + rr * 4;
        WvT[(size_t)(n0 + row) * K2 + k0 + tx] = f2bf(t[tx][row]);
    }
}

// ---------------- qp[b,h] = query[b,:] @ Wq[:,h] ----------------
__global__ __launch_bounds__(256) void qproj_kernel(
        const float* __restrict__ query, const float* __restrict__ Wq,
        float* __restrict__ qp) {
    int b = blockIdx.x >> 2;
    int h = ((blockIdx.x & 3) << 8) + threadIdx.x;
    const float* q = query + (size_t)b * K2;
    float acc = 0.f;
    for (int f = 0; f < K2; f += 4) {
        f32x4 qv = *reinterpret_cast<const f32x4*>(q + f);
        acc += qv.x * Wq[(size_t)f * HD + h];
        acc += qv.y * Wq[(size_t)(f + 1) * HD + h];
        acc += qv.z * Wq[(size_t)(f + 2) * HD + h];
        acc += qv.w * Wq[(size_t)(f + 3) * HD + h];
    }
    qp[b * HD + h] = acc;
}

// ================= 256x256 8-phase GEMM (T2+T3+T4+T5) =================
// BM=BN=256, BK=64, 8 waves (2Mx4N), 512 thr, LDS 128KB dbuf.
// Per-wave out 128x64 -> acc[8][4] f32x4. NT = K2/64 = 32 K-tiles.
// A-tile rows of wave wr live entirely in half wr (rows wr*128..wr*128+127):
//   quad MB=0 reads bytes aRow+f*2048 (wave rows 0..63),
//   quad MB=4 reads bytes aRow+8192+f*2048 (wave rows 64..127).
// Region-safe t+2 staging into buf cur: A-parts p0 in body1 (last read body0),
// B full in body2 (last read body1), A-parts p1 in body3 (last read body2).
#define NT 32

__device__ __forceinline__ f32x4 mfma_bf16(bf16x8 a, bf16x8 b, f32x4 c) {
    return __builtin_amdgcn_mfma_f32_16x16x32_bf16(a, b, c, 0, 0, 0);
}

template<int MB, int NB>
__device__ __forceinline__ void mfma_quad(f32x4 (&acc)[8][4],
        const bf16x8 (&af)[4][2], const bf16x8 (&bfv)[2][2]) {
#pragma unroll
    for (int f = 0; f < 4; ++f)
#pragma unroll
        for (int j = 0; j < 2; ++j) {
            acc[MB + f][NB + j] = mfma_bf16(af[f][0], bfv[j][0], acc[MB + f][NB + j]);
            acc[MB + f][NB + j] = mfma_bf16(af[f][1], bfv[j][1], acc[MB + f][NB + j]);
        }
}

__global__ __launch_bounds__(512, 2) void gemm8_kernel(
        const unsigned short* __restrict__ A,   // [M_TOT,K2] bf16
        const unsigned short* __restrict__ BT,  // [HD,K2] bf16
        unsigned short* __restrict__ Vout) {    // [M_TOT,HD] bf16
    __shared__ __align__(16) char lds[131072];  // A: [2buf][256r][64c]bf16, B at +65536

    const int tid  = threadIdx.x;
    const int lane = tid & 63;
    const int wave = tid >> 6;       // 0..7
    const int wr   = wave >> 2;      // 0..1 (M)
    const int wc   = wave & 3;       // 0..3 (N)

    // XCD-bijective swizzle (nwg=1024, %8==0)
    int id  = blockIdx.x;
    int xcd = id & 7, sdx = id >> 3;
    int m0 = ((xcd << 5) | (sdx >> 2)) * 256;
    int n0 = (sdx & 3) * 256;

    // staging: linear LDS dest, inverse-XOR-swizzled global source (G21)
    const int off0   = wave * 1024 + lane * 16;         // byte within 8K part
    const int srow   = off0 >> 7;                       // 0..63
    const int schunk = ((off0 >> 4) & 7) ^ (srow & 7);  // XOR involution
    const int scol   = schunk * 8;                      // bf16 col within 64
    const unsigned short* As0 = A  + ((size_t)m0 + srow) * K2 + scol;
    const unsigned short* Bs0 = BT + ((size_t)n0 + srow) * K2 + scol;

    // ds-read constants (swizzled read): chunk c -> c ^ (row&7), row&7 == lane&7
    const int l15 = lane & 15, l4v = lane >> 4;
    const int kch0 = (l4v ^ (lane & 7)) << 4;           // k-slice 0
    const int kch1 = ((4 | l4v) ^ (lane & 7)) << 4;     // k-slice 1
    const int aRow = (wr * 128 + l15) * 128;
    const int bRow = (wc * 64 + l15) * 128;

    f32x4 acc[8][4] = {};

    // one 8KB quarter-tile: half h_ (0/1), part p_ (0/1), tile t_, buffer buf_
#define STG_A(t_, h_, p_, buf_) \
    load_lds_16B(As0 + ((size_t)((h_) * 128 + (p_) * 64)) * K2 + (t_) * 64, \
                 lds + (buf_) * 32768 + (h_) * 16384 + (p_) * 8192 + off0)
#define STG_B(t_, h_, p_, buf_) \
    load_lds_16B(Bs0 + ((size_t)((h_) * 128 + (p_) * 64)) * K2 + (t_) * 64, \
                 lds + 65536 + (buf_) * 32768 + (h_) * 16384 + (p_) * 8192 + off0)

    // prologue: tile0 (8 loads) then tile1 (8 loads)
    STG_A(0, 0, 0, 0); STG_A(0, 0, 1, 0); STG_A(0, 1, 0, 0); STG_A(0, 1, 1, 0);
    STG_B(0, 0, 0, 0); STG_B(0, 0, 1, 0); STG_B(0, 1, 0, 0); STG_B(0, 1, 1, 0);
    STG_A(1, 0, 0, 1); STG_A(1, 0, 1, 1); STG_A(1, 1, 0, 1); STG_A(1, 1, 1, 1);
    STG_B(1, 0, 0, 1); STG_B(1, 0, 1, 1); STG_B(1, 1, 0, 1); STG_B(1, 1, 1, 1);
    asm volatile("s_waitcnt vmcnt(8)" ::: "memory");   // tile0 landed
    __builtin_amdgcn_s_barrier();

    bf16x8 afr[4][2], bf0[2][2], bf1[2][2];

    for (int t = 0; t < NT; ++t) {
        const int cur = t & 1;
        const char* La = lds + cur * 32768;
        const char* Lb = lds + 65536 + cur * 32768;
        const bool pf = (t + 2 < NT);

        // ---- body0: ds A(wave rows 0..63) + B(j0,1); MFMA q(0,0) ----
#pragma unroll
        for (int f = 0; f < 4; ++f) {
            afr[f][0] = *(const bf16x8*)(La + aRow + f * 2048 + kch0);
            afr[f][1] = *(const bf16x8*)(La + aRow + f * 2048 + kch1);
        }
#pragma unroll
        for (int j = 0; j < 2; ++j) {
            bf0[j][0] = *(const bf16x8*)(Lb + bRow + j * 2048 + kch0);
            bf0[j][1] = *(const bf16x8*)(Lb + bRow + j * 2048 + kch1);
        }
        __builtin_amdgcn_s_barrier();
        asm volatile("s_waitcnt lgkmcnt(0)" ::: "memory");
        __builtin_amdgcn_s_setprio(1);
        mfma_quad<0, 0>(acc, afr, bf0);
        __builtin_amdgcn_s_setprio(0);
        __builtin_amdgcn_s_barrier();

        // ---- body1: ds B(j2,3); stage A(t+2) p0 halves; MFMA q(0,2) ----
#pragma unroll
        for (int j = 0; j < 2; ++j) {
            bf1[j][0] = *(const bf16x8*)(Lb + bRow + (2 + j) * 2048 + kch0);
            bf1[j][1] = *(const bf16x8*)(Lb + bRow + (2 + j) * 2048 + kch1);
        }
        if (pf) { STG_A(t + 2, 0, 0, cur); STG_A(t + 2, 1, 0, cur); }
        __builtin_amdgcn_s_barrier();
        asm volatile("s_waitcnt lgkmcnt(0)" ::: "memory");
        __builtin_amdgcn_s_setprio(1);
        mfma_quad<0, 2>(acc, afr, bf1);
        __builtin_amdgcn_s_setprio(0);
        __builtin_amdgcn_s_barrier();

        // ---- body2: ds A(wave rows 64..127, +8192); stage B(t+2) full; MFMA q(4,2) ----
#pragma unroll
        for (int f = 0; f < 4; ++f) {
            afr[f][0] = *(const bf16x8*)(La + aRow + 8192 + f * 2048 + kch0);
            afr[f][1] = *(const bf16x8*)(La + aRow + 8192 + f * 2048 + kch1);
        }
        if (pf) {
            STG_B(t + 2, 0, 0, cur); STG_B(t + 2, 0, 1, cur);
            STG_B(t + 2, 1, 0, cur); STG_B(t + 2, 1, 1, cur);
        }
        __builtin_amdgcn_s_barrier();
        asm volatile("s_waitcnt lgkmcnt(0)" ::: "memory");
        __builtin_amdgcn_s_setprio(1);
        mfma_quad<4, 2>(acc, afr, bf1);
        __builtin_amdgcn_s_setprio(0);
        __builtin_amdgcn_s_barrier();

        // ---- body3: stage A(t+2) p1 halves; MFMA q(4,0); counted end-iter wait ----
        if (pf) { STG_A(t + 2, 0, 1, cur); STG_A(t + 2, 1, 1, cur); }
        __builtin_amdgcn_s_barrier();
        __builtin_amdgcn_s_setprio(1);
        mfma_quad<4, 0>(acc, afr, bf0);
        __builtin_amdgcn_s_setprio(0);
        if (t < NT - 1) {
            if (t < NT - 2) asm volatile("s_waitcnt vmcnt(8)" ::: "memory");
            else            asm volatile("s_waitcnt vmcnt(0)" ::: "memory");
            __builtin_amdgcn_s_barrier();
        }
    }
#undef STG_A
#undef STG_B

    // epilogue: C/D layout col=lane&15, row=(lane>>4)*4+reg
#pragma unroll
    for (int fi = 0; fi < 8; ++fi) {
#pragma unroll
        for (int fj = 0; fj < 4; ++fj) {
            int row = m0 + wr * 128 + fi * 16 + l4v * 4;
            int col = n0 + wc * 64 + fj * 16 + l15;
#pragma unroll
            for (int r = 0; r < 4; ++r)
                Vout[(size_t)(row + r) * HD + col] = f2bf(acc[fi][fj][r]);
        }
    }
}

// ---------------- fallback 128^2 GEMM (small ws): fp32 A reg-staged ----------------
#define BM 128
#define BN 128
#define BK 32
__device__ __forceinline__ void swizzle_mn(int id, int& m0, int& n0) {
    int xcd = id & 7;
    int s = id >> 3;
    int m_idx = (xcd << 6) | (s >> 3);
    int n_idx = s & 7;
    m0 = m_idx * BM;
    n0 = n_idx * BN;
}

__global__ __launch_bounds__(256) void gemm_v_kernel(
        const float* __restrict__ A,
        const unsigned short* __restrict__ BT,
        unsigned short* __restrict__ Vout) {
    __shared__ __align__(16) unsigned short As[BM * BK];
    __shared__ __align__(16) unsigned short Bs[BN * BK];
    const int tid = threadIdx.x;
    const int lane = tid & 63;
    const int wave = tid >> 6;
    const int wr = wave >> 1, wc = wave & 1;
    int m0, n0;
    swizzle_mn(blockIdx.x, m0, n0);
    const int l15 = lane & 15;
    const int l4 = lane >> 4;

    f32x4 acc[4][4] = {};

    for (int kk = 0; kk < K2; kk += BK) {
#pragma unroll
        for (int i = 0; i < 4; ++i) {
            int c = i * 256 + tid;
            int row = c >> 3;
            int col = (c & 7) * 4;
            f32x4 v = *reinterpret_cast<const f32x4*>(
                A + (size_t)(m0 + row) * K2 + kk + col);
            u16x4 bv;
            bv.x = f2bf(v.x); bv.y = f2bf(v.y);
            bv.z = f2bf(v.z); bv.w = f2bf(v.w);
            *reinterpret_cast<u16x4*>(&As[row * BK + col]) = bv;
        }
#pragma unroll
        for (int i = 0; i < 2; ++i) {
            int cb = i * 256 + tid;
            int row = cb >> 2, col = (cb & 3) * 8;
            load_lds_16B(BT + (size_t)(n0 + row) * K2 + kk + col, ((char*)Bs) + cb * 16);
        }
        __syncthreads();

        bf16x8 af[4], bfr[4];
#pragma unroll
        for (int i = 0; i < 4; ++i) {
            int row = wr * 64 + i * 16 + l15;
            af[i] = *reinterpret_cast<const bf16x8*>(&As[row * BK + l4 * 8]);
        }
#pragma unroll
        for (int j = 0; j < 4; ++j) {
            int row = wc * 64 + j * 16 + l15;
            bfr[j] = *reinterpret_cast<const bf16x8*>(&Bs[row * BK + l4 * 8]);
        }
#pragma unroll
        for (int i = 0; i < 4; ++i)
#pragma unroll
            for (int j = 0; j < 4; ++j)
                acc[i][j] = __builtin_amdgcn_mfma_f32_16x16x32_bf16(
                    af[i], bfr[j], acc[i][j], 0, 0, 0);
        __syncthreads();
    }

#pragma unroll
    for (int i = 0; i < 4; ++i) {
#pragma unroll
        for (int j = 0; j < 4; ++j) {
            int row = m0 + wr * 64 + i * 16 + l4 * 4;
            int col = n0 + wc * 64 + j * 16 + l15;
#pragma unroll
            for (int r = 0; r < 4; ++r)
                Vout[(size_t)(row + r) * HD + col] = f2bf(acc[i][j][r]);
        }
    }
}

// ---------------- scores[m] = tanh(v + qp + pc*Wc) . We  (coalesced h) ----------------
__global__ __launch_bounds__(256) void score_kernel(
        const unsigned short* __restrict__ V, const float* __restrict__ qp,
        const float* __restrict__ Wc, const float* __restrict__ We,
        const float* __restrict__ pre_cov, float* __restrict__ scores) {
    int lane = threadIdx.x & 63;
    int wave = threadIdx.x >> 6;
    int m = blockIdx.x * 4 + wave;
    int b = m >> 11;
    float pc = pre_cov[m];
    const unsigned short* vp = V + (size_t)m * HD;
    const float* qpb = qp + b * HD;
    float partial = 0.f;
#pragma unroll
    for (int e = 0; e < 16; ++e) {
        int h = e * 64 + lane;
        float f = bf2f(vp[h]) + qpb[h] + pc * Wc[h];
        float t = 1.f - 2.f / (__expf(2.f * f) + 1.f);
        partial += t * We[h];
    }
#pragma unroll
    for (int off = 32; off; off >>= 1)
        partial += __shfl_xor(partial, off);
    if (lane == 0) scores[m] = partial;
}

// ---------------- per-batch softmax + coverage ----------------
__global__ __launch_bounds__(256) void softmax_kernel(
        const float* __restrict__ scores, const unsigned char* __restrict__ mask,
        const float* __restrict__ pre_cov, float* __restrict__ out) {
    __shared__ float red[8];
    int b = blockIdx.x;
    int tid = threadIdx.x;
    int lane = tid & 63, wave = tid >> 6;
    float s[8];
#pragma unroll
    for (int i = 0; i < 8; ++i) {
        int idx = b * SEQ + i * 256 + tid;
        float v = scores[idx];
        if (mask[idx]) v = -INFINITY;
        s[i] = v;
    }
    float mx = s[0];
#pragma unroll
    for (int i = 1; i < 8; ++i) mx = fmaxf(mx, s[i]);
#pragma unroll
    for (int off = 32; off; off >>= 1) mx = fmaxf(mx, __shfl_xor(mx, off));
    if (lane == 0) red[wave] = mx;
    __syncthreads();
    mx = fmaxf(fmaxf(red[0], red[1]), fmaxf(red[2], red[3]));

    float e[8]; float sum = 0.f;
#pragma unroll
    for (int i = 0; i < 8; ++i) { e[i] = __expf(s[i] - mx); sum += e[i]; }
#pragma unroll
    for (int off = 32; off; off >>= 1) sum += __shfl_xor(sum, off);
    if (lane == 0) red[4 + wave] = sum;
    __syncthreads();
    sum = red[4] + red[5] + red[6] + red[7];
    float inv = 1.f / sum;
#pragma unroll
    for (int i = 0; i < 8; ++i) {
        int idx = b * SEQ + i * 256 + tid;
        float a = e[i] * inv;
        out[32768 + idx] = a;                         // alphas
        out[32768 + 65536 + idx] = pre_cov[idx] + a;  // new_coverage
    }
}

// ---------------- context partial sums (deterministic 2-stage) ----------------
__global__ __launch_bounds__(256) void ctx_part_kernel(
        const unsigned short* __restrict__ V, const float* __restrict__ out,
        float* __restrict__ part) {
    int blk = blockIdx.x;          // 32 b * 16 sc * 4 hc = 2048
    int hc = blk & 3;
    int sc = (blk >> 2) & 15;
    int b  = blk >> 6;
    int h = hc * 256 + threadIdx.x;
    const float* al = out + 32768 + b * SEQ + sc * 128;
    const unsigned short* vp = V + ((size_t)(b * SEQ + sc * 128)) * HD + h;
    float acc = 0.f;
#pragma unroll 8
    for (int s = 0; s < 128; ++s)
        acc += al[s] * bf2f(vp[(size_t)s * HD]);
    part[(size_t)(b * 16 + sc) * HD + h] = acc;
}

__global__ __launch_bounds__(256) void ctx_reduce_kernel(
        const float* __restrict__ part, float* __restrict__ out) {
    int idx = blockIdx.x * 256 + threadIdx.x;  // 0..32767
    int b = idx >> 10, h = idx & 1023;
    float acc = 0.f;
#pragma unroll
    for (int sc = 0; sc < 16; ++sc)
        acc += part[(size_t)(b * 16 + sc) * HD + h];
    out[idx] = acc;
}

extern "C" void kernel_launch(void* const* d_in, const int* in_sizes, int n_in,
                              void* d_out, int out_size, void* d_ws, size_t ws_size,
                              hipStream_t stream) {
    const float* value          = (const float*)d_in[0];
    const float* query          = (const float*)d_in[1];
    const unsigned char* mask   = (const unsigned char*)d_in[2];
    const float* pre_cov        = (const float*)d_in[3];
    const float* Wv             = (const float*)d_in[4];
    const float* Wq             = (const float*)d_in[5];
    const float* We             = (const float*)d_in[6];
    const float* Wc             = (const float*)d_in[7];
    float* out = (float*)d_out;

    char* ws = (char*)d_ws;
    // layout: WvT 4MB @0 | Vbf 128MB @4MB | qp @132MB | scores @132M+128K |
    //         part 2MB @132M+384K | Abf 256MB @136MB (Path A only)
    unsigned short* WvT = (unsigned short*)(ws);
    unsigned short* Vbf = (unsigned short*)(ws + ((size_t)4 << 20));
    float* qp           = (float*)(ws + ((size_t)132 << 20));
    float* scores       = (float*)(ws + ((size_t)132 << 20) + (128 << 10));
    float* part         = (float*)(ws + ((size_t)132 << 20) + (384 << 10));
    unsigned short* Abf = (unsigned short*)(ws + ((size_t)136 << 20));

    const bool bigws = ws_size >= ((size_t)392 << 20);

    hipLaunchKernelGGL(wv_transpose_kernel, dim3(16, 32), dim3(256), 0, stream, Wv, WvT);
    hipLaunchKernelGGL(qproj_kernel, dim3(128), dim3(256), 0, stream, query, Wq, qp);
    if (bigws) {
        hipLaunchKernelGGL(cvt_value_kernel, dim3(2048), dim3(256), 0, stream, value, Abf);
        hipLaunchKernelGGL(gemm8_kernel, dim3(1024), dim3(512), 0, stream, Abf, WvT, Vbf);
    } else {
        hipLaunchKernelGGL(gemm_v_kernel, dim3(4096), dim3(256), 0, stream, value, WvT, Vbf);
    }
    hipLaunchKernelGGL(score_kernel, dim3(M_TOT / 4), dim3(256), 0, stream,
                       Vbf, qp, Wc, We, pre_cov, scores);
    hipLaunchKernelGGL(softmax_kernel, dim3(BATCH), dim3(256), 0, stream,
                       scores, mask, pre_cov, out);
    hipLaunchKernelGGL(ctx_part_kernel, dim3(2048), dim3(256), 0, stream, Vbf, out, part);
    hipLaunchKernelGGL(ctx_reduce_kernel, dim3(128), dim3(256), 0, stream, part, out);
}

// Round 8
// 530.603 us; speedup vs baseline: 1.0007x; 1.0007x over previous
//
#include <hip/hip_runtime.h>
#include <hip/hip_bf16.h>

#define HD 1024      // H
#define K2 2048      // 2H
#define BATCH 32
#define SEQ 2048
#define M_TOT (BATCH * SEQ)  // 65536

typedef __attribute__((ext_vector_type(4))) float f32x4;
typedef __attribute__((ext_vector_type(8))) short bf16x8;
typedef __attribute__((ext_vector_type(4))) unsigned short u16x4;
typedef __attribute__((ext_vector_type(8))) unsigned short u16x8;

__device__ __forceinline__ float bf2f(unsigned short u) {
    unsigned int x = ((unsigned int)u) << 16;
    return __builtin_bit_cast(float, x);
}
__device__ __forceinline__ unsigned short f2bf(float f) {
    unsigned int x = __builtin_bit_cast(unsigned int, f);
    unsigned int lsb = (x >> 16) & 1u;
    x += 0x7fffu + lsb;   // round to nearest even
    return (unsigned short)(x >> 16);
}

__device__ __forceinline__ void load_lds_16B(const void* g, void* lds) {
    __builtin_amdgcn_global_load_lds(
        (const __attribute__((address_space(1))) unsigned int*)g,
        (__attribute__((address_space(3))) unsigned int*)lds,
        16, 0, 0);
}

// ---------------- value f32 -> bf16 streaming convert ----------------
__global__ __launch_bounds__(256) void cvt_value_kernel(
        const float* __restrict__ A, unsigned short* __restrict__ Abf) {
    const size_t stride = (size_t)2048 * 256 * 8;
    size_t i = ((size_t)blockIdx.x * 256 + threadIdx.x) * 8;
    const size_t n = (size_t)M_TOT * K2;
    for (; i < n; i += stride) {
        f32x4 a = *reinterpret_cast<const f32x4*>(A + i);
        f32x4 b = *reinterpret_cast<const f32x4*>(A + i + 4);
        u16x8 r;
        r[0] = f2bf(a.x); r[1] = f2bf(a.y); r[2] = f2bf(a.z); r[3] = f2bf(a.w);
        r[4] = f2bf(b.x); r[5] = f2bf(b.y); r[6] = f2bf(b.z); r[7] = f2bf(b.w);
        *reinterpret_cast<u16x8*>(Abf + i) = r;
    }
}

// ---------------- Wv [K2,HD] f32  ->  WvT [HD,K2] bf16 ----------------
__global__ __launch_bounds__(256) void wv_transpose_kernel(
        const float* __restrict__ Wv, unsigned short* __restrict__ WvT) {
    __shared__ float t[64][65];
    int n0 = blockIdx.x * 64;
    int k0 = blockIdx.y * 64;
    int tx = threadIdx.x & 63, ty = threadIdx.x >> 6;
#pragma unroll
    for (int rr = 0; rr < 16; ++rr) {
        int row = ty + rr * 4;
        t[row][tx] = Wv[(size_t)(k0 + row) * HD + n0 + tx];
    }
    __syncthreads();
#pragma unroll
    for (int rr = 0; rr < 16; ++rr) {
        int row = ty + rr * 4;
        WvT[(size_t)(n0 + row) * K2 + k0 + tx] = f2bf(t[tx][row]);
    }
}

// ---------------- qp[b,h] = query[b,:] @ Wq[:,h] ----------------
__global__ __launch_bounds__(256) void qproj_kernel(
        const float* __restrict__ query, const float* __restrict__ Wq,
        float* __restrict__ qp) {
    int b = blockIdx.x >> 2;
    int h = ((blockIdx.x & 3) << 8) + threadIdx.x;
    const float* q = query + (size_t)b * K2;
    float acc = 0.f;
    for (int f = 0; f < K2; f += 4) {
        f32x4 qv = *reinterpret_cast<const f32x4*>(q + f);
        acc += qv.x * Wq[(size_t)f * HD + h];
        acc += qv.y * Wq[(size_t)(f + 1) * HD + h];
        acc += qv.z * Wq[(size_t)(f + 2) * HD + h];
        acc += qv.w * Wq[(size_t)(f + 3) * HD + h];
    }
    qp[b * HD + h] = acc;
}

// ================= 256x256 8-phase GEMM (T2+T3+T4+T5) =================
// BM=BN=256, BK=64, 8 waves (2Mx4N), 512 thr, LDS 128KB dbuf.
// Per-wave out 128x64 -> acc[8][4] f32x4. NT = K2/64 = 32 K-tiles.
// A-tile rows of wave wr live entirely in half wr (rows wr*128..wr*128+127):
//   quad MB=0 reads bytes aRow+f*2048 (wave rows 0..63),
//   quad MB=4 reads bytes aRow+8192+f*2048 (wave rows 64..127).
// Region-safe t+2 staging into buf cur: A-parts p0 in body1 (last read body0),
// B full in body2 (last read body1), A-parts p1 in body3 (last read body2).
#define NT 32

__device__ __forceinline__ f32x4 mfma_bf16(bf16x8 a, bf16x8 b, f32x4 c) {
    return __builtin_amdgcn_mfma_f32_16x16x32_bf16(a, b, c, 0, 0, 0);
}

template<int MB, int NB>
__device__ __forceinline__ void mfma_quad(f32x4 (&acc)[8][4],
        const bf16x8 (&af)[4][2], const bf16x8 (&bfv)[2][2]) {
#pragma unroll
    for (int f = 0; f < 4; ++f)
#pragma unroll
        for (int j = 0; j < 2; ++j) {
            acc[MB + f][NB + j] = mfma_bf16(af[f][0], bfv[j][0], acc[MB + f][NB + j]);
            acc[MB + f][NB + j] = mfma_bf16(af[f][1], bfv[j][1], acc[MB + f][NB + j]);
        }
}

__global__ __launch_bounds__(512, 2) void gemm8_kernel(
        const unsigned short* __restrict__ A,   // [M_TOT,K2] bf16
        const unsigned short* __restrict__ BT,  // [HD,K2] bf16
        unsigned short* __restrict__ Vout) {    // [M_TOT,HD] bf16
    __shared__ __align__(16) char lds[131072];  // A: [2buf][256r][64c]bf16, B at +65536

    const int tid  = threadIdx.x;
    const int lane = tid & 63;
    const int wave = tid >> 6;       // 0..7
    const int wr   = wave >> 2;      // 0..1 (M)
    const int wc   = wave & 3;       // 0..3 (N)

    // XCD-bijective swizzle (nwg=1024, %8==0)
    int id  = blockIdx.x;
    int xcd = id & 7, sdx = id >> 3;
    int m0 = ((xcd << 5) | (sdx >> 2)) * 256;
    int n0 = (sdx & 3) * 256;

    // staging: linear LDS dest, inverse-XOR-swizzled global source (G21)
    const int off0   = wave * 1024 + lane * 16;         // byte within 8K part
    const int srow   = off0 >> 7;                       // 0..63
    const int schunk = ((off0 >> 4) & 7) ^ (srow & 7);  // XOR involution
    const int scol   = schunk * 8;                      // bf16 col within 64
    const unsigned short* As0 = A  + ((size_t)m0 + srow) * K2 + scol;
    const unsigned short* Bs0 = BT + ((size_t)n0 + srow) * K2 + scol;

    // ds-read constants (swizzled read): chunk c -> c ^ (row&7), row&7 == lane&7
    const int l15 = lane & 15, l4v = lane >> 4;
    const int kch0 = (l4v ^ (lane & 7)) << 4;           // k-slice 0
    const int kch1 = ((4 | l4v) ^ (lane & 7)) << 4;     // k-slice 1
    const int aRow = (wr * 128 + l15) * 128;
    const int bRow = (wc * 64 + l15) * 128;

    f32x4 acc[8][4] = {};

    // one 8KB quarter-tile: half h_ (0/1), part p_ (0/1), tile t_, buffer buf_
#define STG_A(t_, h_, p_, buf_) \
    load_lds_16B(As0 + ((size_t)((h_) * 128 + (p_) * 64)) * K2 + (t_) * 64, \
                 lds + (buf_) * 32768 + (h_) * 16384 + (p_) * 8192 + off0)
#define STG_B(t_, h_, p_, buf_) \
    load_lds_16B(Bs0 + ((size_t)((h_) * 128 + (p_) * 64)) * K2 + (t_) * 64, \
                 lds + 65536 + (buf_) * 32768 + (h_) * 16384 + (p_) * 8192 + off0)

    // prologue: tile0 (8 loads) then tile1 (8 loads)
    STG_A(0, 0, 0, 0); STG_A(0, 0, 1, 0); STG_A(0, 1, 0, 0); STG_A(0, 1, 1, 0);
    STG_B(0, 0, 0, 0); STG_B(0, 0, 1, 0); STG_B(0, 1, 0, 0); STG_B(0, 1, 1, 0);
    STG_A(1, 0, 0, 1); STG_A(1, 0, 1, 1); STG_A(1, 1, 0, 1); STG_A(1, 1, 1, 1);
    STG_B(1, 0, 0, 1); STG_B(1, 0, 1, 1); STG_B(1, 1, 0, 1); STG_B(1, 1, 1, 1);
    asm volatile("s_waitcnt vmcnt(8)" ::: "memory");   // tile0 landed
    __builtin_amdgcn_s_barrier();

    bf16x8 afr[4][2], bf0[2][2], bf1[2][2];

    for (int t = 0; t < NT; ++t) {
        const int cur = t & 1;
        const char* La = lds + cur * 32768;
        const char* Lb = lds + 65536 + cur * 32768;
        const bool pf = (t + 2 < NT);

        // ---- body0: ds A(wave rows 0..63) + B(j0,1); MFMA q(0,0) ----
#pragma unroll
        for (int f = 0; f < 4; ++f) {
            afr[f][0] = *(const bf16x8*)(La + aRow + f * 2048 + kch0);
            afr[f][1] = *(const bf16x8*)(La + aRow + f * 2048 + kch1);
        }
#pragma unroll
        for (int j = 0; j < 2; ++j) {
            bf0[j][0] = *(const bf16x8*)(Lb + bRow + j * 2048 + kch0);
            bf0[j][1] = *(const bf16x8*)(Lb + bRow + j * 2048 + kch1);
        }
        __builtin_amdgcn_s_barrier();
        asm volatile("s_waitcnt lgkmcnt(0)" ::: "memory");
        __builtin_amdgcn_s_setprio(1);
        mfma_quad<0, 0>(acc, afr, bf0);
        __builtin_amdgcn_s_setprio(0);
        __builtin_amdgcn_s_barrier();

        // ---- body1: ds B(j2,3); stage A(t+2) p0 halves; MFMA q(0,2) ----
#pragma unroll
        for (int j = 0; j < 2; ++j) {
            bf1[j][0] = *(const bf16x8*)(Lb + bRow + (2 + j) * 2048 + kch0);
            bf1[j][1] = *(const bf16x8*)(Lb + bRow + (2 + j) * 2048 + kch1);
        }
        if (pf) { STG_A(t + 2, 0, 0, cur); STG_A(t + 2, 1, 0, cur); }
        __builtin_amdgcn_s_barrier();
        asm volatile("s_waitcnt lgkmcnt(0)" ::: "memory");
        __builtin_amdgcn_s_setprio(1);
        mfma_quad<0, 2>(acc, afr, bf1);
        __builtin_amdgcn_s_setprio(0);
        __builtin_amdgcn_s_barrier();

        // ---- body2: ds A(wave rows 64..127, +8192); stage B(t+2) full; MFMA q(4,2) ----
#pragma unroll
        for (int f = 0; f < 4; ++f) {
            afr[f][0] = *(const bf16x8*)(La + aRow + 8192 + f * 2048 + kch0);
            afr[f][1] = *(const bf16x8*)(La + aRow + 8192 + f * 2048 + kch1);
        }
        if (pf) {
            STG_B(t + 2, 0, 0, cur); STG_B(t + 2, 0, 1, cur);
            STG_B(t + 2, 1, 0, cur); STG_B(t + 2, 1, 1, cur);
        }
        __builtin_amdgcn_s_barrier();
        asm volatile("s_waitcnt lgkmcnt(0)" ::: "memory");
        __builtin_amdgcn_s_setprio(1);
        mfma_quad<4, 2>(acc, afr, bf1);
        __builtin_amdgcn_s_setprio(0);
        __builtin_amdgcn_s_barrier();

        // ---- body3: stage A(t+2) p1 halves; MFMA q(4,0); counted end-iter wait ----
        if (pf) { STG_A(t + 2, 0, 1, cur); STG_A(t + 2, 1, 1, cur); }
        __builtin_amdgcn_s_barrier();
        __builtin_amdgcn_s_setprio(1);
        mfma_quad<4, 0>(acc, afr, bf0);
        __builtin_amdgcn_s_setprio(0);
        if (t < NT - 1) {
            if (t < NT - 2) asm volatile("s_waitcnt vmcnt(8)" ::: "memory");
            else            asm volatile("s_waitcnt vmcnt(0)" ::: "memory");
            __builtin_amdgcn_s_barrier();
        }
    }
#undef STG_A
#undef STG_B

    // epilogue: C/D layout col=lane&15, row=(lane>>4)*4+reg
#pragma unroll
    for (int fi = 0; fi < 8; ++fi) {
#pragma unroll
        for (int fj = 0; fj < 4; ++fj) {
            int row = m0 + wr * 128 + fi * 16 + l4v * 4;
            int col = n0 + wc * 64 + fj * 16 + l15;
#pragma unroll
            for (int r = 0; r < 4; ++r)
                Vout[(size_t)(row + r) * HD + col] = f2bf(acc[fi][fj][r]);
        }
    }
}

// ---------------- fallback 128^2 GEMM (small ws): fp32 A reg-staged ----------------
#define BM 128
#define BN 128
#define BK 32
__device__ __forceinline__ void swizzle_mn(int id, int& m0, int& n0) {
    int xcd = id & 7;
    int s = id >> 3;
    int m_idx = (xcd << 6) | (s >> 3);
    int n_idx = s & 7;
    m0 = m_idx * BM;
    n0 = n_idx * BN;
}

__global__ __launch_bounds__(256) void gemm_v_kernel(
        const float* __restrict__ A,
        const unsigned short* __restrict__ BT,
        unsigned short* __restrict__ Vout) {
    __shared__ __align__(16) unsigned short As[BM * BK];
    __shared__ __align__(16) unsigned short Bs[BN * BK];
    const int tid = threadIdx.x;
    const int lane = tid & 63;
    const int wave = tid >> 6;
    const int wr = wave >> 1, wc = wave & 1;
    int m0, n0;
    swizzle_mn(blockIdx.x, m0, n0);
    const int l15 = lane & 15;
    const int l4 = lane >> 4;

    f32x4 acc[4][4] = {};

    for (int kk = 0; kk < K2; kk += BK) {
#pragma unroll
        for (int i = 0; i < 4; ++i) {
            int c = i * 256 + tid;
            int row = c >> 3;
            int col = (c & 7) * 4;
            f32x4 v = *reinterpret_cast<const f32x4*>(
                A + (size_t)(m0 + row) * K2 + kk + col);
            u16x4 bv;
            bv.x = f2bf(v.x); bv.y = f2bf(v.y);
            bv.z = f2bf(v.z); bv.w = f2bf(v.w);
            *reinterpret_cast<u16x4*>(&As[row * BK + col]) = bv;
        }
#pragma unroll
        for (int i = 0; i < 2; ++i) {
            int cb = i * 256 + tid;
            int row = cb >> 2, col = (cb & 3) * 8;
            load_lds_16B(BT + (size_t)(n0 + row) * K2 + kk + col, ((char*)Bs) + cb * 16);
        }
        __syncthreads();

        bf16x8 af[4], bfr[4];
#pragma unroll
        for (int i = 0; i < 4; ++i) {
            int row = wr * 64 + i * 16 + l15;
            af[i] = *reinterpret_cast<const bf16x8*>(&As[row * BK + l4 * 8]);
        }
#pragma unroll
        for (int j = 0; j < 4; ++j) {
            int row = wc * 64 + j * 16 + l15;
            bfr[j] = *reinterpret_cast<const bf16x8*>(&Bs[row * BK + l4 * 8]);
        }
#pragma unroll
        for (int i = 0; i < 4; ++i)
#pragma unroll
            for (int j = 0; j < 4; ++j)
                acc[i][j] = __builtin_amdgcn_mfma_f32_16x16x32_bf16(
                    af[i], bfr[j], acc[i][j], 0, 0, 0);
        __syncthreads();
    }

#pragma unroll
    for (int i = 0; i < 4; ++i) {
#pragma unroll
        for (int j = 0; j < 4; ++j) {
            int row = m0 + wr * 64 + i * 16 + l4 * 4;
            int col = n0 + wc * 64 + j * 16 + l15;
#pragma unroll
            for (int r = 0; r < 4; ++r)
                Vout[(size_t)(row + r) * HD + col] = f2bf(acc[i][j][r]);
        }
    }
}

// ---------------- scores[m] = tanh(v + qp + pc*Wc) . We  (coalesced h) ----------------
__global__ __launch_bounds__(256) void score_kernel(
        const unsigned short* __restrict__ V, const float* __restrict__ qp,
        const float* __restrict__ Wc, const float* __restrict__ We,
        const float* __restrict__ pre_cov, float* __restrict__ scores) {
    int lane = threadIdx.x & 63;
    int wave = threadIdx.x >> 6;
    int m = blockIdx.x * 4 + wave;
    int b = m >> 11;
    float pc = pre_cov[m];
    const unsigned short* vp = V + (size_t)m * HD;
    const float* qpb = qp + b * HD;
    float partial = 0.f;
#pragma unroll
    for (int e = 0; e < 16; ++e) {
        int h = e * 64 + lane;
        float f = bf2f(vp[h]) + qpb[h] + pc * Wc[h];
        float t = 1.f - 2.f / (__expf(2.f * f) + 1.f);
        partial += t * We[h];
    }
#pragma unroll
    for (int off = 32; off; off >>= 1)
        partial += __shfl_xor(partial, off);
    if (lane == 0) scores[m] = partial;
}

// ---------------- per-batch softmax + coverage ----------------
__global__ __launch_bounds__(256) void softmax_kernel(
        const float* __restrict__ scores, const unsigned char* __restrict__ mask,
        const float* __restrict__ pre_cov, float* __restrict__ out) {
    __shared__ float red[8];
    int b = blockIdx.x;
    int tid = threadIdx.x;
    int lane = tid & 63, wave = tid >> 6;
    float s[8];
#pragma unroll
    for (int i = 0; i < 8; ++i) {
        int idx = b * SEQ + i * 256 + tid;
        float v = scores[idx];
        if (mask[idx]) v = -INFINITY;
        s[i] = v;
    }
    float mx = s[0];
#pragma unroll
    for (int i = 1; i < 8; ++i) mx = fmaxf(mx, s[i]);
#pragma unroll
    for (int off = 32; off; off >>= 1) mx = fmaxf(mx, __shfl_xor(mx, off));
    if (lane == 0) red[wave] = mx;
    __syncthreads();
    mx = fmaxf(fmaxf(red[0], red[1]), fmaxf(red[2], red[3]));

    float e[8]; float sum = 0.f;
#pragma unroll
    for (int i = 0; i < 8; ++i) { e[i] = __expf(s[i] - mx); sum += e[i]; }
#pragma unroll
    for (int off = 32; off; off >>= 1) sum += __shfl_xor(sum, off);
    if (lane == 0) red[4 + wave] = sum;
    __syncthreads();
    sum = red[4] + red[5] + red[6] + red[7];
    float inv = 1.f / sum;
#pragma unroll
    for (int i = 0; i < 8; ++i) {
        int idx = b * SEQ + i * 256 + tid;
        float a = e[i] * inv;
        out[32768 + idx] = a;                         // alphas
        out[32768 + 65536 + idx] = pre_cov[idx] + a;  // new_coverage
    }
}

// ---------------- context partial sums (deterministic 2-stage) ----------------
__global__ __launch_bounds__(256) void ctx_part_kernel(
        const unsigned short* __restrict__ V, const float* __restrict__ out,
        float* __restrict__ part) {
    int blk = blockIdx.x;          // 32 b * 16 sc * 4 hc = 2048
    int hc = blk & 3;
    int sc = (blk >> 2) & 15;
    int b  = blk >> 6;
    int h = hc * 256 + threadIdx.x;
    const float* al = out + 32768 + b * SEQ + sc * 128;
    const unsigned short* vp = V + ((size_t)(b * SEQ + sc * 128)) * HD + h;
    float acc = 0.f;
#pragma unroll 8
    for (int s = 0; s < 128; ++s)
        acc += al[s] * bf2f(vp[(size_t)s * HD]);
    part[(size_t)(b * 16 + sc) * HD + h] = acc;
}

__global__ __launch_bounds__(256) void ctx_reduce_kernel(
        const float* __restrict__ part, float* __restrict__ out) {
    int idx = blockIdx.x * 256 + threadIdx.x;  // 0..32767
    int b = idx >> 10, h = idx & 1023;
    float acc = 0.f;
#pragma unroll
    for (int sc = 0; sc < 16; ++sc)
        acc += part[(size_t)(b * 16 + sc) * HD + h];
    out[idx] = acc;
}

extern "C" void kernel_launch(void* const* d_in, const int* in_sizes, int n_in,
                              void* d_out, int out_size, void* d_ws, size_t ws_size,
                              hipStream_t stream) {
    const float* value          = (const float*)d_in[0];
    const float* query          = (const float*)d_in[1];
    const unsigned char* mask   = (const unsigned char*)d_in[2];
    const float* pre_cov        = (const float*)d_in[3];
    const float* Wv             = (const float*)d_in[4];
    const float* Wq             = (const float*)d_in[5];
    const float* We             = (const float*)d_in[6];
    const float* Wc             = (const float*)d_in[7];
    float* out = (float*)d_out;

    char* ws = (char*)d_ws;
    // layout: WvT 4MB @0 | Vbf 128MB @4MB | qp @132MB | scores @132M+128K |
    //         part 2MB @132M+384K | Abf 256MB @136MB (Path A only)
    unsigned short* WvT = (unsigned short*)(ws);
    unsigned short* Vbf = (unsigned short*)(ws + ((size_t)4 << 20));
    float* qp           = (float*)(ws + ((size_t)132 << 20));
    float* scores       = (float*)(ws + ((size_t)132 << 20) + (128 << 10));
    float* part         = (float*)(ws + ((size_t)132 << 20) + (384 << 10));
    unsigned short* Abf = (unsigned short*)(ws + ((size_t)136 << 20));

    const bool bigws = ws_size >= ((size_t)392 << 20);

    hipLaunchKernelGGL(wv_transpose_kernel, dim3(16, 32), dim3(256), 0, stream, Wv, WvT);
    hipLaunchKernelGGL(qproj_kernel, dim3(128), dim3(256), 0, stream, query, Wq, qp);
    if (bigws) {
        hipLaunchKernelGGL(cvt_value_kernel, dim3(2048), dim3(256), 0, stream, value, Abf);
        hipLaunchKernelGGL(gemm8_kernel, dim3(1024), dim3(512), 0, stream, Abf, WvT, Vbf);
    } else {
        hipLaunchKernelGGL(gemm_v_kernel, dim3(4096), dim3(256), 0, stream, value, WvT, Vbf);
    }
    hipLaunchKernelGGL(score_kernel, dim3(M_TOT / 4), dim3(256), 0, stream,
                       Vbf, qp, Wc, We, pre_cov, scores);
    hipLaunchKernelGGL(softmax_kernel, dim3(BATCH), dim3(256), 0, stream,
                       scores, mask, pre_cov, out);
    hipLaunchKernelGGL(ctx_part_kernel, dim3(2048), dim3(256), 0, stream, Vbf, out, part);
    hipLaunchKernelGGL(ctx_reduce_kernel, dim3(128), dim3(256), 0, stream, part, out);
}

// Round 9
// 503.950 us; speedup vs baseline: 1.0536x; 1.0529x over previous
//
#include <hip/hip_runtime.h>
#include <hip/hip_bf16.h>

#define HD 1024      // H
#define K2 2048      // 2H
#define BATCH 32
#define SEQ 2048
#define M_TOT (BATCH * SEQ)  // 65536

typedef __attribute__((ext_vector_type(4))) float f32x4;
typedef __attribute__((ext_vector_type(8))) short bf16x8;
typedef __attribute__((ext_vector_type(4))) unsigned short u16x4;
typedef __attribute__((ext_vector_type(8))) unsigned short u16x8;
typedef __attribute__((ext_vector_type(4))) unsigned int u32x4;

__device__ __forceinline__ float bf2f(unsigned short u) {
    unsigned int x = ((unsigned int)u) << 16;
    return __builtin_bit_cast(float, x);
}
__device__ __forceinline__ unsigned short f2bf(float f) {
    unsigned int x = __builtin_bit_cast(unsigned int, f);
    unsigned int lsb = (x >> 16) & 1u;
    x += 0x7fffu + lsb;   // round to nearest even
    return (unsigned short)(x >> 16);
}
__device__ __forceinline__ unsigned int cvt_pk(float lo, float hi) {
    unsigned int r;
    asm("v_cvt_pk_bf16_f32 %0, %1, %2" : "=v"(r) : "v"(lo), "v"(hi));
    return r;
}

__device__ __forceinline__ void load_lds_16B(const void* g, void* lds) {
    __builtin_amdgcn_global_load_lds(
        (const __attribute__((address_space(1))) unsigned int*)g,
        (__attribute__((address_space(3))) unsigned int*)lds,
        16, 0, 0);
}

// ---------------- Wv [K2,HD] f32  ->  WvT [HD,K2] bf16 ----------------
__global__ __launch_bounds__(256) void wv_transpose_kernel(
        const float* __restrict__ Wv, unsigned short* __restrict__ WvT) {
    __shared__ float t[64][65];
    int n0 = blockIdx.x * 64;
    int k0 = blockIdx.y * 64;
    int tx = threadIdx.x & 63, ty = threadIdx.x >> 6;
#pragma unroll
    for (int rr = 0; rr < 16; ++rr) {
        int row = ty + rr * 4;
        t[row][tx] = Wv[(size_t)(k0 + row) * HD + n0 + tx];
    }
    __syncthreads();
#pragma unroll
    for (int rr = 0; rr < 16; ++rr) {
        int row = ty + rr * 4;
        WvT[(size_t)(n0 + row) * K2 + k0 + tx] = f2bf(t[tx][row]);
    }
}

// ---------------- qp[b,h] = query[b,:] @ Wq[:,h] ----------------
__global__ __launch_bounds__(256) void qproj_kernel(
        const float* __restrict__ query, const float* __restrict__ Wq,
        float* __restrict__ qp) {
    int b = blockIdx.x >> 2;
    int h = ((blockIdx.x & 3) << 8) + threadIdx.x;
    const float* q = query + (size_t)b * K2;
    float acc = 0.f;
    for (int f = 0; f < K2; f += 4) {
        f32x4 qv = *reinterpret_cast<const f32x4*>(q + f);
        acc += qv.x * Wq[(size_t)f * HD + h];
        acc += qv.y * Wq[(size_t)(f + 1) * HD + h];
        acc += qv.z * Wq[(size_t)(f + 2) * HD + h];
        acc += qv.w * Wq[(size_t)(f + 3) * HD + h];
    }
    qp[b * HD + h] = acc;
}

// ================= 256x256 8-phase GEMM, fused fp32->bf16 A-staging =================
// BM=BN=256, BK=64, 8 waves (2Mx4N), 512 thr, LDS 128KB dbuf.
// A: reg-staged (global_load_dwordx4 fp32 -> v_cvt_pk_bf16_f32 -> swizzled ds_write_b128).
//    Loads for tile t+2 issued body0; p0 written body2 (p0 last read body0),
//    p1 written body3 (p1 last read body2). Compiler inserts counted vmcnt for
//    the reg-load consumes; since B(t+1) gload_lds are OLDER in the vmcnt FIFO,
//    those waits transitively guarantee B(t+1) has landed (no explicit end-iter
//    vmcnt needed except t==NT-2 drain for B(NT-1)).
// B: global_load_lds, linear dest + inverse-swizzled source (G21), staged body2
//    (B buf last read body1).
#define NT 32

__device__ __forceinline__ f32x4 mfma_bf16(bf16x8 a, bf16x8 b, f32x4 c) {
    return __builtin_amdgcn_mfma_f32_16x16x32_bf16(a, b, c, 0, 0, 0);
}

template<int MB, int NB>
__device__ __forceinline__ void mfma_quad(f32x4 (&acc)[8][4],
        const bf16x8 (&af)[4][2], const bf16x8 (&bfv)[2][2]) {
#pragma unroll
    for (int f = 0; f < 4; ++f)
#pragma unroll
        for (int j = 0; j < 2; ++j) {
            acc[MB + f][NB + j] = mfma_bf16(af[f][0], bfv[j][0], acc[MB + f][NB + j]);
            acc[MB + f][NB + j] = mfma_bf16(af[f][1], bfv[j][1], acc[MB + f][NB + j]);
        }
}

__global__ __launch_bounds__(512, 2) void gemm8_kernel(
        const float* __restrict__ A,            // value [M_TOT,K2] f32
        const unsigned short* __restrict__ BT,  // WvT [HD,K2] bf16
        unsigned short* __restrict__ Vout) {    // v [M_TOT,HD] bf16
    __shared__ __align__(16) char lds[131072];  // A: [2buf][256r][64c]bf16, B at +65536

    const int tid  = threadIdx.x;
    const int lane = tid & 63;
    const int wave = tid >> 6;       // 0..7
    const int wr   = wave >> 2;      // 0..1 (M)
    const int wc   = wave & 3;       // 0..3 (N)

    // XCD-bijective swizzle (nwg=1024, %8==0)
    int id  = blockIdx.x;
    int xcd = id & 7, sdx = id >> 3;
    int m0 = ((xcd << 5) | (sdx >> 2)) * 256;
    int n0 = (sdx & 3) * 256;

    // per-thread staging geometry (8KB part = 64 rows x 64 bf16 cols)
    const int off0   = wave * 1024 + lane * 16;         // linear byte in part
    const int srow   = off0 >> 7;                       // 0..63
    const int chunk  = (off0 >> 4) & 7;
    const int schunk = chunk ^ (srow & 7);              // XOR involution
    // B: gload_lds linear dest + inverse-swizzled global source
    const unsigned short* Bs0 = BT + ((size_t)n0 + srow) * K2 + schunk * 8;
    // A: linear fp32 global source; ds_write to swizzled LDS byte
    const float* aBase = A + ((size_t)m0 + srow) * K2 + chunk * 8;
    const int woff = srow * 128 + schunk * 16;          // swizzled byte in part

    // ds-read constants (swizzled read)
    const int l15 = lane & 15, l4v = lane >> 4;
    const int kch0 = (l4v ^ (lane & 7)) << 4;
    const int kch1 = ((4 | l4v) ^ (lane & 7)) << 4;
    const int aRow = (wr * 128 + l15) * 128;
    const int bRow = (wc * 64 + l15) * 128;

    f32x4 acc[8][4] = {};

    // A-tile reg loads: 4 units (h,p): u0=(0,0) u1=(1,0) u2=(0,1) u3=(1,1)
    f32x4 a0lo, a0hi, a1lo, a1hi, a2lo, a2hi, a3lo, a3hi;

#define LOAD_A(t_) do {                                                       \
        const float* _ap = aBase + (size_t)(t_) * 64;                         \
        a0lo = *(const f32x4*)(_ap);                                          \
        a0hi = *(const f32x4*)(_ap + 4);                                      \
        a1lo = *(const f32x4*)(_ap + (size_t)128 * K2);                       \
        a1hi = *(const f32x4*)(_ap + (size_t)128 * K2 + 4);                   \
        a2lo = *(const f32x4*)(_ap + (size_t)64 * K2);                        \
        a2hi = *(const f32x4*)(_ap + (size_t)64 * K2 + 4);                    \
        a3lo = *(const f32x4*)(_ap + (size_t)192 * K2);                       \
        a3hi = *(const f32x4*)(_ap + (size_t)192 * K2 + 4);                   \
    } while (0)

#define WRITE_A_P0(buf_) do {                                                 \
        u32x4 w0, w1;                                                         \
        w0.x = cvt_pk(a0lo.x, a0lo.y); w0.y = cvt_pk(a0lo.z, a0lo.w);         \
        w0.z = cvt_pk(a0hi.x, a0hi.y); w0.w = cvt_pk(a0hi.z, a0hi.w);         \
        w1.x = cvt_pk(a1lo.x, a1lo.y); w1.y = cvt_pk(a1lo.z, a1lo.w);         \
        w1.z = cvt_pk(a1hi.x, a1hi.y); w1.w = cvt_pk(a1hi.z, a1hi.w);         \
        *reinterpret_cast<u32x4*>(lds + (buf_) * 32768 + 0     + woff) = w0;  \
        *reinterpret_cast<u32x4*>(lds + (buf_) * 32768 + 16384 + woff) = w1;  \
    } while (0)

#define WRITE_A_P1(buf_) do {                                                 \
        u32x4 w2, w3;                                                         \
        w2.x = cvt_pk(a2lo.x, a2lo.y); w2.y = cvt_pk(a2lo.z, a2lo.w);         \
        w2.z = cvt_pk(a2hi.x, a2hi.y); w2.w = cvt_pk(a2hi.z, a2hi.w);         \
        w3.x = cvt_pk(a3lo.x, a3lo.y); w3.y = cvt_pk(a3lo.z, a3lo.w);         \
        w3.z = cvt_pk(a3hi.x, a3hi.y); w3.w = cvt_pk(a3hi.z, a3hi.w);         \
        *reinterpret_cast<u32x4*>(lds + (buf_) * 32768 + 8192  + woff) = w2;  \
        *reinterpret_cast<u32x4*>(lds + (buf_) * 32768 + 24576 + woff) = w3;  \
    } while (0)

#define STG_B(t_, h_, p_, buf_) \
    load_lds_16B(Bs0 + ((size_t)((h_) * 128 + (p_) * 64)) * K2 + (t_) * 64, \
                 lds + 65536 + (buf_) * 32768 + (h_) * 16384 + (p_) * 8192 + off0)

    // prologue: tiles 0 and 1 fully staged
    LOAD_A(0);
    STG_B(0, 0, 0, 0); STG_B(0, 0, 1, 0); STG_B(0, 1, 0, 0); STG_B(0, 1, 1, 0);
    WRITE_A_P0(0); WRITE_A_P1(0);
    LOAD_A(1);
    STG_B(1, 0, 0, 1); STG_B(1, 0, 1, 1); STG_B(1, 1, 0, 1); STG_B(1, 1, 1, 1);
    WRITE_A_P0(1); WRITE_A_P1(1);
    asm volatile("s_waitcnt vmcnt(0) lgkmcnt(0)" ::: "memory");
    __builtin_amdgcn_s_barrier();

    bf16x8 afr[4][2], bf0[2][2], bf1[2][2];

    for (int t = 0; t < NT; ++t) {
        const int cur = t & 1;
        const char* La = lds + cur * 32768;
        const char* Lb = lds + 65536 + cur * 32768;
        const bool pf = (t + 2 < NT);

        // ---- body0: ds A rows 0..63 + B(j0,1); issue A(t+2) reg loads; MFMA q(0,0) ----
#pragma unroll
        for (int f = 0; f < 4; ++f) {
            afr[f][0] = *(const bf16x8*)(La + aRow + f * 2048 + kch0);
            afr[f][1] = *(const bf16x8*)(La + aRow + f * 2048 + kch1);
        }
#pragma unroll
        for (int j = 0; j < 2; ++j) {
            bf0[j][0] = *(const bf16x8*)(Lb + bRow + j * 2048 + kch0);
            bf0[j][1] = *(const bf16x8*)(Lb + bRow + j * 2048 + kch1);
        }
        if (pf) LOAD_A(t + 2);
        __builtin_amdgcn_s_barrier();
        asm volatile("s_waitcnt lgkmcnt(0)" ::: "memory");
        __builtin_amdgcn_s_setprio(1);
        mfma_quad<0, 0>(acc, afr, bf0);
        __builtin_amdgcn_s_setprio(0);
        __builtin_amdgcn_s_barrier();

        // ---- body1: ds B(j2,3); MFMA q(0,2) ----
#pragma unroll
        for (int j = 0; j < 2; ++j) {
            bf1[j][0] = *(const bf16x8*)(Lb + bRow + (2 + j) * 2048 + kch0);
            bf1[j][1] = *(const bf16x8*)(Lb + bRow + (2 + j) * 2048 + kch1);
        }
        __builtin_amdgcn_s_barrier();
        asm volatile("s_waitcnt lgkmcnt(0)" ::: "memory");
        __builtin_amdgcn_s_setprio(1);
        mfma_quad<0, 2>(acc, afr, bf1);
        __builtin_amdgcn_s_setprio(0);
        __builtin_amdgcn_s_barrier();

        // ---- body2: ds A rows 64..127; cvt+write A(t+2) p0; stage B(t+2); MFMA q(4,2) ----
#pragma unroll
        for (int f = 0; f < 4; ++f) {
            afr[f][0] = *(const bf16x8*)(La + aRow + 8192 + f * 2048 + kch0);
            afr[f][1] = *(const bf16x8*)(La + aRow + 8192 + f * 2048 + kch1);
        }
        if (pf) {
            WRITE_A_P0(cur);   // compiler-counted vmcnt drains B(t+1) first (FIFO-older)
            STG_B(t + 2, 0, 0, cur); STG_B(t + 2, 0, 1, cur);
            STG_B(t + 2, 1, 0, cur); STG_B(t + 2, 1, 1, cur);
        }
        __builtin_amdgcn_s_barrier();
        asm volatile("s_waitcnt lgkmcnt(0)" ::: "memory");
        __builtin_amdgcn_s_setprio(1);
        mfma_quad<4, 2>(acc, afr, bf1);
        __builtin_amdgcn_s_setprio(0);
        __builtin_amdgcn_s_barrier();

        // ---- body3: cvt+write A(t+2) p1; MFMA q(4,0); drain at NT-2 ----
        if (pf) WRITE_A_P1(cur);
        __builtin_amdgcn_s_barrier();
        asm volatile("s_waitcnt lgkmcnt(0)" ::: "memory");
        __builtin_amdgcn_s_setprio(1);
        mfma_quad<4, 0>(acc, afr, bf0);
        __builtin_amdgcn_s_setprio(0);
        if (t == NT - 2) asm volatile("s_waitcnt vmcnt(0)" ::: "memory");
        if (t < NT - 1) __builtin_amdgcn_s_barrier();
    }
#undef LOAD_A
#undef WRITE_A_P0
#undef WRITE_A_P1
#undef STG_B

    // epilogue: C/D layout col=lane&15, row=(lane>>4)*4+reg
#pragma unroll
    for (int fi = 0; fi < 8; ++fi) {
#pragma unroll
        for (int fj = 0; fj < 4; ++fj) {
            int row = m0 + wr * 128 + fi * 16 + l4v * 4;
            int col = n0 + wc * 64 + fj * 16 + l15;
#pragma unroll
            for (int r = 0; r < 4; ++r)
                Vout[(size_t)(row + r) * HD + col] = f2bf(acc[fi][fj][r]);
        }
    }
}

// ---------------- fallback 128^2 GEMM (small ws): fp32 A reg-staged ----------------
#define BM 128
#define BN 128
#define BK 32
__device__ __forceinline__ void swizzle_mn(int id, int& m0, int& n0) {
    int xcd = id & 7;
    int s = id >> 3;
    int m_idx = (xcd << 6) | (s >> 3);
    int n_idx = s & 7;
    m0 = m_idx * BM;
    n0 = n_idx * BN;
}

__global__ __launch_bounds__(256) void gemm_v_kernel(
        const float* __restrict__ A,
        const unsigned short* __restrict__ BT,
        unsigned short* __restrict__ Vout) {
    __shared__ __align__(16) unsigned short As[BM * BK];
    __shared__ __align__(16) unsigned short Bs[BN * BK];
    const int tid = threadIdx.x;
    const int lane = tid & 63;
    const int wave = tid >> 6;
    const int wr = wave >> 1, wc = wave & 1;
    int m0, n0;
    swizzle_mn(blockIdx.x, m0, n0);
    const int l15 = lane & 15;
    const int l4 = lane >> 4;

    f32x4 acc[4][4] = {};

    for (int kk = 0; kk < K2; kk += BK) {
#pragma unroll
        for (int i = 0; i < 4; ++i) {
            int c = i * 256 + tid;
            int row = c >> 3;
            int col = (c & 7) * 4;
            f32x4 v = *reinterpret_cast<const f32x4*>(
                A + (size_t)(m0 + row) * K2 + kk + col);
            u16x4 bv;
            bv.x = f2bf(v.x); bv.y = f2bf(v.y);
            bv.z = f2bf(v.z); bv.w = f2bf(v.w);
            *reinterpret_cast<u16x4*>(&As[row * BK + col]) = bv;
        }
#pragma unroll
        for (int i = 0; i < 2; ++i) {
            int cb = i * 256 + tid;
            int row = cb >> 2, col = (cb & 3) * 8;
            load_lds_16B(BT + (size_t)(n0 + row) * K2 + kk + col, ((char*)Bs) + cb * 16);
        }
        __syncthreads();

        bf16x8 af[4], bfr[4];
#pragma unroll
        for (int i = 0; i < 4; ++i) {
            int row = wr * 64 + i * 16 + l15;
            af[i] = *reinterpret_cast<const bf16x8*>(&As[row * BK + l4 * 8]);
        }
#pragma unroll
        for (int j = 0; j < 4; ++j) {
            int row = wc * 64 + j * 16 + l15;
            bfr[j] = *reinterpret_cast<const bf16x8*>(&Bs[row * BK + l4 * 8]);
        }
#pragma unroll
        for (int i = 0; i < 4; ++i)
#pragma unroll
            for (int j = 0; j < 4; ++j)
                acc[i][j] = __builtin_amdgcn_mfma_f32_16x16x32_bf16(
                    af[i], bfr[j], acc[i][j], 0, 0, 0);
        __syncthreads();
    }

#pragma unroll
    for (int i = 0; i < 4; ++i) {
#pragma unroll
        for (int j = 0; j < 4; ++j) {
            int row = m0 + wr * 64 + i * 16 + l4 * 4;
            int col = n0 + wc * 64 + j * 16 + l15;
#pragma unroll
            for (int r = 0; r < 4; ++r)
                Vout[(size_t)(row + r) * HD + col] = f2bf(acc[i][j][r]);
        }
    }
}

// ---------------- scores[m] = tanh(v + qp + pc*Wc) . We  (coalesced h) ----------------
__global__ __launch_bounds__(256) void score_kernel(
        const unsigned short* __restrict__ V, const float* __restrict__ qp,
        const float* __restrict__ Wc, const float* __restrict__ We,
        const float* __restrict__ pre_cov, float* __restrict__ scores) {
    int lane = threadIdx.x & 63;
    int wave = threadIdx.x >> 6;
    int m = blockIdx.x * 4 + wave;
    int b = m >> 11;
    float pc = pre_cov[m];
    const unsigned short* vp = V + (size_t)m * HD;
    const float* qpb = qp + b * HD;
    float partial = 0.f;
#pragma unroll
    for (int e = 0; e < 16; ++e) {
        int h = e * 64 + lane;
        float f = bf2f(vp[h]) + qpb[h] + pc * Wc[h];
        float t = 1.f - 2.f / (__expf(2.f * f) + 1.f);
        partial += t * We[h];
    }
#pragma unroll
    for (int off = 32; off; off >>= 1)
        partial += __shfl_xor(partial, off);
    if (lane == 0) scores[m] = partial;
}

// ---------------- per-batch softmax + coverage ----------------
__global__ __launch_bounds__(256) void softmax_kernel(
        const float* __restrict__ scores, const unsigned char* __restrict__ mask,
        const float* __restrict__ pre_cov, float* __restrict__ out) {
    __shared__ float red[8];
    int b = blockIdx.x;
    int tid = threadIdx.x;
    int lane = tid & 63, wave = tid >> 6;
    float s[8];
#pragma unroll
    for (int i = 0; i < 8; ++i) {
        int idx = b * SEQ + i * 256 + tid;
        float v = scores[idx];
        if (mask[idx]) v = -INFINITY;
        s[i] = v;
    }
    float mx = s[0];
#pragma unroll
    for (int i = 1; i < 8; ++i) mx = fmaxf(mx, s[i]);
#pragma unroll
    for (int off = 32; off; off >>= 1) mx = fmaxf(mx, __shfl_xor(mx, off));
    if (lane == 0) red[wave] = mx;
    __syncthreads();
    mx = fmaxf(fmaxf(red[0], red[1]), fmaxf(red[2], red[3]));

    float e[8]; float sum = 0.f;
#pragma unroll
    for (int i = 0; i < 8; ++i) { e[i] = __expf(s[i] - mx); sum += e[i]; }
#pragma unroll
    for (int off = 32; off; off >>= 1) sum += __shfl_xor(sum, off);
    if (lane == 0) red[4 + wave] = sum;
    __syncthreads();
    sum = red[4] + red[5] + red[6] + red[7];
    float inv = 1.f / sum;
#pragma unroll
    for (int i = 0; i < 8; ++i) {
        int idx = b * SEQ + i * 256 + tid;
        float a = e[i] * inv;
        out[32768 + idx] = a;                         // alphas
        out[32768 + 65536 + idx] = pre_cov[idx] + a;  // new_coverage
    }
}

// ---------------- context partial sums (deterministic 2-stage, u16x4 loads) ----------------
__global__ __launch_bounds__(256) void ctx_part_kernel(
        const unsigned short* __restrict__ V, const float* __restrict__ out,
        float* __restrict__ part) {
    int blk = blockIdx.x;          // 512 = 32 b * 16 sc
    int sc = blk & 15;
    int b  = blk >> 4;
    int h4 = threadIdx.x * 4;
    const float* al = out + 32768 + b * SEQ + sc * 128;
    const unsigned short* vp = V + ((size_t)(b * SEQ + sc * 128)) * HD + h4;
    f32x4 acc = {};
#pragma unroll 4
    for (int s = 0; s < 128; ++s) {
        float a = al[s];
        u16x4 v = *reinterpret_cast<const u16x4*>(vp + (size_t)s * HD);
        acc.x += a * bf2f(v.x);
        acc.y += a * bf2f(v.y);
        acc.z += a * bf2f(v.z);
        acc.w += a * bf2f(v.w);
    }
    *reinterpret_cast<f32x4*>(&part[(size_t)(b * 16 + sc) * HD + h4]) = acc;
}

__global__ __launch_bounds__(256) void ctx_reduce_kernel(
        const float* __restrict__ part, float* __restrict__ out) {
    int idx = blockIdx.x * 256 + threadIdx.x;  // 0..32767
    int b = idx >> 10, h = idx & 1023;
    float acc = 0.f;
#pragma unroll
    for (int sc = 0; sc < 16; ++sc)
        acc += part[(size_t)(b * 16 + sc) * HD + h];
    out[idx] = acc;
}

extern "C" void kernel_launch(void* const* d_in, const int* in_sizes, int n_in,
                              void* d_out, int out_size, void* d_ws, size_t ws_size,
                              hipStream_t stream) {
    const float* value          = (const float*)d_in[0];
    const float* query          = (const float*)d_in[1];
    const unsigned char* mask   = (const unsigned char*)d_in[2];
    const float* pre_cov        = (const float*)d_in[3];
    const float* Wv             = (const float*)d_in[4];
    const float* Wq             = (const float*)d_in[5];
    const float* We             = (const float*)d_in[6];
    const float* Wc             = (const float*)d_in[7];
    float* out = (float*)d_out;

    char* ws = (char*)d_ws;
    // layout: WvT 4MB @0 | Vbf 128MB @4MB | qp @132MB | scores @132M+128K | part 2MB @132M+384K
    unsigned short* WvT = (unsigned short*)(ws);
    unsigned short* Vbf = (unsigned short*)(ws + ((size_t)4 << 20));
    float* qp           = (float*)(ws + ((size_t)132 << 20));
    float* scores       = (float*)(ws + ((size_t)132 << 20) + (128 << 10));
    float* part         = (float*)(ws + ((size_t)132 << 20) + (384 << 10));

    const bool bigws = ws_size >= ((size_t)136 << 20);

    hipLaunchKernelGGL(wv_transpose_kernel, dim3(16, 32), dim3(256), 0, stream, Wv, WvT);
    hipLaunchKernelGGL(qproj_kernel, dim3(128), dim3(256), 0, stream, query, Wq, qp);
    if (bigws) {
        hipLaunchKernelGGL(gemm8_kernel, dim3(1024), dim3(512), 0, stream, value, WvT, Vbf);
    } else {
        hipLaunchKernelGGL(gemm_v_kernel, dim3(4096), dim3(256), 0, stream, value, WvT, Vbf);
    }
    hipLaunchKernelGGL(score_kernel, dim3(M_TOT / 4), dim3(256), 0, stream,
                       Vbf, qp, Wc, We, pre_cov, scores);
    hipLaunchKernelGGL(softmax_kernel, dim3(BATCH), dim3(256), 0, stream,
                       scores, mask, pre_cov, out);
    hipLaunchKernelGGL(ctx_part_kernel, dim3(512), dim3(256), 0, stream, Vbf, out, part);
    hipLaunchKernelGGL(ctx_reduce_kernel, dim3(128), dim3(256), 0, stream, part, out);
}